// Round 1
// baseline (2836.077 us; speedup 1.0000x reference)
//
#include <hip/hip_runtime.h>
#include <cstddef>
#include <cstdint>

// DynamicGPCM: B=4096 sequences, S=512 steps, D=16, K=5, H=256, IN=37.
// Outputs (f32, concat): theta(B,S,16) | alpha(B,S,16) | beta(B,S,4) | logits(B,S,5) | probs(B,S,5)

namespace {
constexpr int Bn = 4096;
constexpr int Sn = 512;
constexpr int Dn = 16;
constexpr int Hn = 256;
constexpr int INn = 37;
constexpr int Qn = 1000;
constexpr int SEQ = 16;   // sequences per block (4 per wave)

__device__ __forceinline__ float ftanh(float x) {
  return 1.0f - 2.0f / (__expf(2.0f * x) + 1.0f);
}
__device__ __forceinline__ float fsigmoid(float x) {
  return 1.0f / (1.0f + __expf(-x));
}
__device__ __forceinline__ float fsoftplus(float x) {
  return (x > 20.0f) ? x : log1pf(__expf(x));
}

// Intra-wave LDS fence: all seq-group comms are within one wave (16 lanes/seq),
// so a full barrier is unnecessary; drain LDS + block compiler reordering.
#define WAVE_FENCE() asm volatile("s_waitcnt lgkmcnt(0)" ::: "memory")

// ---- Kernel A: per-question item parameters (Q+1 = 1001 rows, tiny) ----
__global__ void precompute_kernel(const float* __restrict__ alpha_raw,
                                  const float* __restrict__ beta_base,
                                  const float* __restrict__ beta_gaps,
                                  float* __restrict__ alpha_q,
                                  float* __restrict__ beta_q) {
  int tid = blockIdx.x * 256 + threadIdx.x;
  if (tid < (Qn + 1) * Dn) alpha_q[tid] = __expf(0.3f * alpha_raw[tid]);
  if (tid < Qn + 1) {
    float base = beta_base[tid];
    float sp0 = fsoftplus(beta_gaps[tid * 3 + 0]);
    float sp1 = fsoftplus(beta_gaps[tid * 3 + 1]);
    float sp2 = fsoftplus(beta_gaps[tid * 3 + 2]);
    beta_q[tid * 4 + 0] = base;
    beta_q[tid * 4 + 1] = base + sp0;
    beta_q[tid * 4 + 2] = base + sp0 + sp1;
    beta_q[tid * 4 + 3] = base + sp0 + sp1 + sp2;
  }
}

// ---- Kernel B: gather alpha/beta output tensors, fully coalesced ----
__global__ void itemout_kernel(const int* __restrict__ questions,
                               const float4* __restrict__ alpha_q4,
                               const float4* __restrict__ beta_q4,
                               float4* __restrict__ out_alpha4,
                               float4* __restrict__ out_beta4) {
  int tid = blockIdx.x * 256 + threadIdx.x;  // [0, B*S*4)
  int pos = tid >> 2, j = tid & 3;
  if (pos >= Bn * Sn) return;
  int q = questions[pos];
  out_alpha4[(size_t)pos * 4 + j] = alpha_q4[(size_t)q * 4 + j];
  if (j == 0) out_beta4[pos] = beta_q4[q];
}

// ---- Kernel C: the recurrent scan. 256 threads = 16 seqs x 16 dims ----
__global__ __launch_bounds__(256, 1) void scan_kernel(
    const float* __restrict__ theta_embed,
    const float* __restrict__ W_h, const float* __restrict__ b_h,
    const float* __restrict__ W_g, const float* __restrict__ b_g,
    const float* __restrict__ W_d, const float* __restrict__ b_d,
    const int* __restrict__ student_ids, const int* __restrict__ questions,
    const int* __restrict__ responses,
    const float* __restrict__ alpha_q, const float4* __restrict__ beta_q4,
    float* __restrict__ out_theta, float* __restrict__ out_logits,
    float* __restrict__ out_probs) {
  // LDS: 37888 + 2*16640 + 16640 + 2432 = 90240 B -> 1 block/CU
  __shared__ float sWh[INn * Hn];     // [i][j], row-major, 256-stride
  __shared__ float sWgT[Dn * 260];    // transposed + pad 260: [d][j]
  __shared__ float sWdT[Dn * 260];
  __shared__ float sH[SEQ * 260];     // h per seq, pad 260 (bank spread)
  __shared__ float sU[SEQ * 38];      // u per seq (37 + pad)

  const int tid = threadIdx.x;
  for (int i = tid; i < INn * Hn; i += 256) sWh[i] = W_h[i];
  for (int i = tid; i < Hn * Dn; i += 256) {
    int j = i >> 4, dd = i & 15;
    sWgT[dd * 260 + j] = W_g[i];
    sWdT[dd * 260 + j] = W_d[i];
  }
  __syncthreads();

  const int seq = tid >> 4;
  const int d = tid & 15;
  const int b = blockIdx.x * SEQ + seq;
  const int* qrow = questions + (size_t)b * Sn;
  const int* rrow = responses + (size_t)b * Sn;

  // theta0 from student_ids[:, 0] only (ABILITY_SCALE = 1)
  float th = theta_embed[(size_t)student_ids[(size_t)b * Sn] * Dn + d];
  const float bg = b_g[d];
  const float bdv = b_d[d];
  const float4* bh4 = (const float4*)b_h;
  const float4 bh0 = bh4[d], bh1 = bh4[16 + d], bh2 = bh4[32 + d], bh3 = bh4[48 + d];

  float* uS = &sU[seq * 38];
  const float4* hrow = (const float4*)&sH[seq * 260];
  float4* hw = (float4*)&sH[seq * 260];
  const float4* wgr = (const float4*)&sWgT[d * 260];
  const float4* wdr = (const float4*)&sWdT[d * 260];

  int q = qrow[0];
  int r = rrow[0];
  float a = alpha_q[(size_t)q * Dn + d];
  float4 bq = beta_q4[q];

  for (int t = 0; t < Sn; ++t) {
    const int tn = (t + 1 < Sn) ? t + 1 : t;
    const int qn = qrow[tn];          // prefetch next-step indices early
    const int rn = rrow[tn];

    // z = <a, theta> over the 16 lanes of this seq (masks < 16 stay in-group)
    float z = a * th;
    z += __shfl_xor(z, 1);
    z += __shfl_xor(z, 2);
    z += __shfl_xor(z, 4);
    z += __shfl_xor(z, 8);

    const float l1 = z - bq.x;
    const float l2 = l1 + z - bq.y;
    const float l3 = l2 + z - bq.z;
    const float l4 = l3 + z - bq.w;
    const float m = fmaxf(fmaxf(fmaxf(l1, l2), fmaxf(l3, l4)), 0.0f);
    const float e0 = __expf(-m);
    const float e1 = __expf(l1 - m);
    const float e2 = __expf(l2 - m);
    const float e3 = __expf(l3 - m);
    const float e4 = __expf(l4 - m);
    const float inv = 1.0f / (e0 + e1 + e2 + e3 + e4);
    const float expected = (e1 + 2.0f * e2 + 3.0f * e3 + 4.0f * e4) * inv;
    const float surprise = (float)r - expected;

    const size_t pos = (size_t)b * Sn + t;
    out_theta[pos * Dn + d] = th;     // pre-update theta
    if (d < 5) {
      float lv = (d == 0) ? 0.0f : (d == 1) ? l1 : (d == 2) ? l2 : (d == 3) ? l3 : l4;
      float ev = (d == 0) ? e0 : (d == 1) ? e1 : (d == 2) ? e2 : (d == 3) ? e3 : e4;
      out_logits[pos * 5 + d] = lv;
      out_probs[pos * 5 + d] = ev * inv;
    }

    // u = [theta(16), surprise(1), a(16), b(4)]
    uS[d] = th;
    uS[17 + d] = a;
    if (d == 0) uS[16] = surprise;
    if (d < 4) uS[33 + d] = (d == 0) ? bq.x : (d == 1) ? bq.y : (d == 2) ? bq.z : bq.w;
    WAVE_FENCE();

    // prefetch next-step item params (vmcnt ops; not blocked by lgkm fence)
    const float an = alpha_q[(size_t)qn * Dn + d];
    const float4 bqn = beta_q4[qn];

    // h[j] for j in {4d+64g}: 4 float4 accumulators, W from LDS (<=2-way banks)
    float4 acc0 = bh0, acc1 = bh1, acc2 = bh2, acc3 = bh3;
    for (int i = 0; i < INn; ++i) {
      const float ui = uS[i];
      const float4* wr = (const float4*)&sWh[i * Hn];
      const float4 w0 = wr[d];
      const float4 w1 = wr[16 + d];
      const float4 w2 = wr[32 + d];
      const float4 w3 = wr[48 + d];
      acc0.x += ui * w0.x; acc0.y += ui * w0.y; acc0.z += ui * w0.z; acc0.w += ui * w0.w;
      acc1.x += ui * w1.x; acc1.y += ui * w1.y; acc1.z += ui * w1.z; acc1.w += ui * w1.w;
      acc2.x += ui * w2.x; acc2.y += ui * w2.y; acc2.z += ui * w2.z; acc2.w += ui * w2.w;
      acc3.x += ui * w3.x; acc3.y += ui * w3.y; acc3.z += ui * w3.z; acc3.w += ui * w3.w;
    }
    float4 h0, h1, h2, h3;
    h0.x = ftanh(acc0.x); h0.y = ftanh(acc0.y); h0.z = ftanh(acc0.z); h0.w = ftanh(acc0.w);
    h1.x = ftanh(acc1.x); h1.y = ftanh(acc1.y); h1.z = ftanh(acc1.z); h1.w = ftanh(acc1.w);
    h2.x = ftanh(acc2.x); h2.y = ftanh(acc2.y); h2.z = ftanh(acc2.z); h2.w = ftanh(acc2.w);
    h3.x = ftanh(acc3.x); h3.y = ftanh(acc3.y); h3.z = ftanh(acc3.z); h3.w = ftanh(acc3.w);
    hw[d] = h0; hw[16 + d] = h1; hw[32 + d] = h2; hw[48 + d] = h3;
    WAVE_FENCE();

    // gate[d], delta[d] = reductions over all 256 h
    float ga = bg, de = bdv;
    for (int jj = 0; jj < 64; ++jj) {
      const float4 hv = hrow[jj];
      const float4 gw = wgr[jj];
      const float4 dw = wdr[jj];
      ga += hv.x * gw.x + hv.y * gw.y + hv.z * gw.z + hv.w * gw.w;
      de += hv.x * dw.x + hv.y * dw.y + hv.z * dw.z + hv.w * dw.w;
    }
    th += fsigmoid(ga) * ftanh(de);

    q = qn; r = rn; a = an; bq = bqn;
  }
  (void)q; (void)r;
}

}  // namespace

extern "C" void kernel_launch(void* const* d_in, const int* in_sizes, int n_in,
                              void* d_out, int out_size, void* d_ws, size_t ws_size,
                              hipStream_t stream) {
  const float* theta_embed = (const float*)d_in[0];
  const float* alpha_raw   = (const float*)d_in[1];
  const float* beta_base   = (const float*)d_in[2];
  const float* beta_gaps   = (const float*)d_in[3];
  const float* W_h = (const float*)d_in[4];
  const float* b_h = (const float*)d_in[5];
  const float* W_g = (const float*)d_in[6];
  const float* b_g = (const float*)d_in[7];
  const float* W_d = (const float*)d_in[8];
  const float* b_d = (const float*)d_in[9];
  const int* student_ids = (const int*)d_in[10];
  const int* questions   = (const int*)d_in[11];
  const int* responses   = (const int*)d_in[12];

  float* out = (float*)d_out;
  float* out_theta  = out;
  float* out_alpha  = out_theta + (size_t)Bn * Sn * Dn;   // 33554432
  float* out_beta   = out_alpha + (size_t)Bn * Sn * Dn;   // 67108864
  float* out_logits = out_beta  + (size_t)Bn * Sn * 4;    // 75497472
  float* out_probs  = out_logits + (size_t)Bn * Sn * 5;   // 85983232

  float* alpha_q = (float*)d_ws;                          // (Q+1)*16 floats
  float* beta_q  = alpha_q + (size_t)(Qn + 1) * Dn;       // (Q+1)*4 floats (16B aligned)

  hipLaunchKernelGGL(precompute_kernel, dim3(63), dim3(256), 0, stream,
                     alpha_raw, beta_base, beta_gaps, alpha_q, beta_q);
  hipLaunchKernelGGL(itemout_kernel, dim3((Bn * Sn * 4) / 256), dim3(256), 0, stream,
                     questions, (const float4*)alpha_q, (const float4*)beta_q,
                     (float4*)out_alpha, (float4*)out_beta);
  hipLaunchKernelGGL(scan_kernel, dim3(Bn / SEQ), dim3(256), 0, stream,
                     theta_embed, W_h, b_h, W_g, b_g, W_d, b_d,
                     student_ids, questions, responses,
                     alpha_q, (const float4*)beta_q,
                     out_theta, out_logits, out_probs);
}